// Round 1
// baseline (43.349 us; speedup 1.0000x reference)
//
#include <hip/hip_runtime.h>
#include <hip/hip_bf16.h>
#include <math.h>

// y[n,o] = min_i (x[n,i] + w[o,i]) + bias[o]
// x: (32768, 128) f32, w: (128,128) f32, bias: (128,) f32, out: (32768,128) f32

constexpr int IN  = 128;
constexpr int OUT = 128;
constexpr int ROWS_PER_WAVE  = 4;
constexpr int WAVES_PER_BLK  = 4;
constexpr int GROUPS_PER_BLK = 4;
constexpr int ROWS_PER_BLK   = ROWS_PER_WAVE * WAVES_PER_BLK * GROUPS_PER_BLK; // 64

__global__ __launch_bounds__(256, 2)
void minplus_kernel(const float* __restrict__ x,
                    const float* __restrict__ w,
                    const float* __restrict__ bias,
                    float* __restrict__ out,
                    int nrows)
{
    // Weight in LDS, row-major, XOR-swizzled within each 512B row so that
    // per-lane ds_read_b128 of "my row o" is bank-conflict-free across lanes.
    __shared__ float wlds[OUT * IN]; // 64 KiB

    const int tid = threadIdx.x;

    // Stage weight: 16384 floats / 256 threads = 64 floats = 16 float4 per thread.
    #pragma unroll
    for (int v = 0; v < 16; ++v) {
        int chunk = v * 256 + tid;        // float4 chunk index, 0..4095
        int flat  = chunk * 4;            // element index
        int o  = flat >> 7;               // row (0..127)
        int ic = flat & 127;              // col (multiple of 4)
        float4 d = *reinterpret_cast<const float4*>(w + flat);
        int byte = o * 512 + ((ic * 4) ^ ((o & 31) << 4));
        *reinterpret_cast<float4*>(reinterpret_cast<char*>(wlds) + byte) = d;
    }
    __syncthreads();

    const int lane = tid & 63;
    const int wave = tid >> 6;
    const int o0 = lane;
    const int o1 = lane + 64;
    const char* wb0 = reinterpret_cast<const char*>(wlds) + o0 * 512;
    const char* wb1 = reinterpret_cast<const char*>(wlds) + o1 * 512;
    const int sw0 = (o0 & 31) << 4;
    const int sw1 = (o1 & 31) << 4;

    const float b0 = bias[o0];
    const float b1 = bias[o1];

    for (int g = 0; g < GROUPS_PER_BLK; ++g) {
        int row0 = blockIdx.x * ROWS_PER_BLK + g * (ROWS_PER_WAVE * WAVES_PER_BLK)
                 + wave * ROWS_PER_WAVE;
        row0 = __builtin_amdgcn_readfirstlane(row0); // wave-uniform -> s_load path
        const float* __restrict__ xr = x + (size_t)row0 * IN;

        float acc[ROWS_PER_WAVE][2];
        #pragma unroll
        for (int r = 0; r < ROWS_PER_WAVE; ++r) {
            acc[r][0] = INFINITY;
            acc[r][1] = INFINITY;
        }

        #pragma unroll
        for (int it = 0; it < IN / 4; ++it) {
            float4 w0 = *reinterpret_cast<const float4*>(wb0 + ((it * 16) ^ sw0));
            float4 w1 = *reinterpret_cast<const float4*>(wb1 + ((it * 16) ^ sw1));
            #pragma unroll
            for (int r = 0; r < ROWS_PER_WAVE; ++r) {
                float4 xv = *reinterpret_cast<const float4*>(xr + r * IN + it * 4);
                // min3 fusion: fminf(fminf(a,b),c) -> v_min3_f32
                acc[r][0] = fminf(fminf(acc[r][0], xv.x + w0.x), xv.y + w0.y);
                acc[r][0] = fminf(fminf(acc[r][0], xv.z + w0.z), xv.w + w0.w);
                acc[r][1] = fminf(fminf(acc[r][1], xv.x + w1.x), xv.y + w1.y);
                acc[r][1] = fminf(fminf(acc[r][1], xv.z + w1.z), xv.w + w1.w);
            }
        }

        #pragma unroll
        for (int r = 0; r < ROWS_PER_WAVE; ++r) {
            out[(size_t)(row0 + r) * OUT + o0] = acc[r][0] + b0;
            out[(size_t)(row0 + r) * OUT + o1] = acc[r][1] + b1;
        }
    }
}

extern "C" void kernel_launch(void* const* d_in, const int* in_sizes, int n_in,
                              void* d_out, int out_size, void* d_ws, size_t ws_size,
                              hipStream_t stream) {
    const float* x    = (const float*)d_in[0];
    const float* w    = (const float*)d_in[1];
    const float* bias = (const float*)d_in[2];
    float* out = (float*)d_out;

    int nrows = in_sizes[0] / IN; // 32768
    int blocks = nrows / ROWS_PER_BLK; // 512
    minplus_kernel<<<blocks, 256, 0, stream>>>(x, w, bias, out, nrows);
}

// Round 2
// 29.269 us; speedup vs baseline: 1.4810x; 1.4810x over previous
//
#include <hip/hip_runtime.h>
#include <hip/hip_bf16.h>
#include <math.h>

// y[n,o] = min_i (x[n,i] + w[o,i]) + bias[o]
// x: (32768,128) f32, w: (128,128) f32, bias: (128,) f32, out: (32768,128) f32

constexpr int K  = 128;
constexpr int BM = 64;   // rows per block
constexpr int BN = 64;   // cols per block

__global__ __launch_bounds__(256, 2)
void minplus_kernel(const float* __restrict__ x,
                    const float* __restrict__ w,
                    const float* __restrict__ bias,
                    float* __restrict__ out)
{
    // x-tile and w-tile, row-major 512B rows, XOR-swizzled: element (row, kbyte)
    // lives at row*512 + (kbyte ^ ((row&7)<<4)). Keeps 16B alignment (bits 4-6).
    __shared__ char lds[(BM + BN) * 512];   // 64 KiB -> 2 blocks/CU
    char* xs = lds;
    char* ws = lds + BM * 512;

    const int tid = threadIdx.x;
    const int rt  = blockIdx.x >> 1;   // row tile (0..511)
    const int ct  = blockIdx.x & 1;    // col tile (0..1)

    // ---- stage x (64x128) and w (64x128) tiles, swizzled ----
    {
        const float* xsrc = x + (size_t)rt * BM * K;
        const float* wsrc = w + (size_t)ct * BN * K;
        #pragma unroll
        for (int rnd = 0; rnd < 8; ++rnd) {
            int chunk = rnd * 256 + tid;    // 16B-chunk index 0..2047
            int row   = chunk >> 5;         // 0..63
            int q     = chunk & 31;         // 16B chunk within row
            float4 xv = *(const float4*)(xsrc + row * K + q * 4);
            float4 wv = *(const float4*)(wsrc + row * K + q * 4);
            int b = row * 512 + ((q * 16) ^ ((row & 7) << 4));
            *(float4*)(xs + b) = xv;
            *(float4*)(ws + b) = wv;
        }
    }
    __syncthreads();

    // thread (ty, tx): owns rows rt*64 + ty + 16m, cols ct*64 + tx + 16n (m,n=0..3)
    const int ty = tid >> 4;    // 0..15
    const int tx = tid & 15;    // 0..15
    const char* xb = xs + ty * 512;
    const char* wb = ws + tx * 512;
    const int swx = (ty & 7) << 4;
    const int sww = (tx & 7) << 4;

    float acc[4][4];
    #pragma unroll
    for (int m = 0; m < 4; ++m)
        #pragma unroll
        for (int n = 0; n < 4; ++n)
            acc[m][n] = INFINITY;

    #pragma unroll 4
    for (int kq = 0; kq < 32; ++kq) {
        int xo = (kq * 16) ^ swx;   // 1 v_xor, shared by 4 reads (imm offsets)
        int wo = (kq * 16) ^ sww;
        float4 xv[4], wv[4];
        #pragma unroll
        for (int m = 0; m < 4; ++m)
            xv[m] = *(const float4*)(xb + m * (16 * 512) + xo);
        #pragma unroll
        for (int n = 0; n < 4; ++n)
            wv[n] = *(const float4*)(wb + n * (16 * 512) + wo);

        #pragma unroll
        for (int m = 0; m < 4; ++m)
            #pragma unroll
            for (int n = 0; n < 4; ++n) {
                float a = acc[m][n];
                // fminf(fminf(a,b),c) -> v_min3_f32
                a = fminf(fminf(a, xv[m].x + wv[n].x), xv[m].y + wv[n].y);
                a = fminf(fminf(a, xv[m].z + wv[n].z), xv[m].w + wv[n].w);
                acc[m][n] = a;
            }
    }

    // ---- epilogue: bias + store ----
    const int rowbase = rt * BM + ty;
    const int colbase = ct * BN + tx;
    #pragma unroll
    for (int n = 0; n < 4; ++n) {
        float b = bias[colbase + 16 * n];
        #pragma unroll
        for (int m = 0; m < 4; ++m) {
            out[(size_t)(rowbase + 16 * m) * 128 + colbase + 16 * n] = acc[m][n] + b;
        }
    }
}

extern "C" void kernel_launch(void* const* d_in, const int* in_sizes, int n_in,
                              void* d_out, int out_size, void* d_ws, size_t ws_size,
                              hipStream_t stream) {
    const float* x    = (const float*)d_in[0];
    const float* w    = (const float*)d_in[1];
    const float* bias = (const float*)d_in[2];
    float* out = (float*)d_out;

    int nrows  = in_sizes[0] / K;          // 32768
    int blocks = (nrows / BM) * (128 / BN); // 1024
    minplus_kernel<<<blocks, 256, 0, stream>>>(x, w, bias, out);
}